// Round 12
// baseline (105.097 us; speedup 1.0000x reference)
//
#include <hip/hip_runtime.h>

#define NPIX   65536
#define HB     128
#define EPSF   1e-6f
#define ROWB   80              /* 32 px * 2B = 64B data + 16B pad (5 x 16B) */
#define MATB   (HB * ROWB)     /* 10240 B per matrix */
#define BUFB   (3 * MATB)      /* 30720 B per buffer set */
#define PPW    24576           /* parts u32 words per block: 3*128*128/2 */
#define NCHUNK 32              /* chunks per (img,b) -> 256 blocks total */

typedef _Float16 half8  __attribute__((ext_vector_type(8)));
typedef __fp16   fp16x2 __attribute__((ext_vector_type(2)));
typedef float    f32x16 __attribute__((ext_vector_type(16)));
typedef float    f32x2  __attribute__((ext_vector_type(2)));

__device__ __forceinline__ unsigned pk2(float a, float b) {
    union { fp16x2 h; unsigned u; } cv;
    cv.h = __builtin_amdgcn_cvt_pkrtz(a, b);
    return cv.u;
}

/* ---------------- kernel 1: 12-wave MFMA histogram --------------------
 * Per (img,b): 3 fields -> K_rg, K_rb, K_gb (sqrt(w) folded).
 * G0=K_rg^T K_rb, G1=K_rg^T K_gb, G2=K_rb^T K_gb (bin-flips cancel).
 * KEY (r12): 768 thr / 12 waves; each wave owns ONE 64x64 tile of ONE
 * gemm -> acc = 64 AGPR + ~65 VGPR = ~130/wave; launch_bounds(768,3)
 * -> 3 waves/SIMD co-resident (r10 was 316 regs = 1 wave/SIMD, pipes
 * serialized; r11's 64x32 tiles raised LDS reads 1.5x).  Gen sharing
 * stays 1x: 3 full matrices in LDS serve all 12 waves.  32-px regions,
 * dbuf, one barrier per region, setprio on MFMA quads.  Grid = 256 =
 * exactly 1 block/CU. */
__global__ __launch_bounds__(768, 3) void hist_mfma(
    const float* __restrict__ pred, const float* __restrict__ tgt,
    unsigned* __restrict__ parts, float* __restrict__ norms, int nchunk)
{
    __shared__ char smat[2 * BUFB];               /* 61440 B */
    __shared__ float wsum[12];

    const int t    = threadIdx.x;
    const int lane = t & 63;
    const int wave = t >> 6;                      /* 0..11 */
    const int chunk = blockIdx.x % nchunk;
    const int ib    = blockIdx.x / nchunk;        /* img*4 + b */
    const int b     = ib & 3;
    const int img   = ib >> 2;
    const int kchunk = NPIX / nchunk;             /* 2048 */
    const int nreg   = kchunk >> 5;               /* 64 regions, even */

    const float* __restrict__ base = (img ? tgt : pred) + (size_t)b * 3 * NPIX;
    const float* __restrict__ Rp = base;
    const float* __restrict__ Gp = base + NPIX;
    const float* __restrict__ Bp = base + 2 * NPIX;

    /* gen role: thread -> mat (t>>8), row set rbase+16s, px pair i16 */
    const int   mat     = t >> 8;                 /* 0..2, wave-uniform */
    const int   tp      = t & 255;
    const int   i16     = tp & 15;                /* px pair index */
    const int   rbase   = tp >> 4;                /* 0..15 */
    const float MU0     = (float)rbase * (300.0f / 127.0f) - 150.0f;
    const float MUSTEP  = 16.0f * (300.0f / 127.0f);
    char* genp0 = smat + mat * MATB + rbase * ROWB + i16 * 4;
    char* genp1 = genp0 + BUFB;

    /* mfma role: wave -> (gemm g, tile i2,j2); A/B matrix ids per gemm */
    const int g    = wave >> 2;                   /* 0..2 */
    const int i2   = (wave >> 1) & 1;
    const int j2   = wave & 1;
    const int Amat = (g == 2) ? 1 : 0;            /* g0,g1: K_rg; g2: K_rb */
    const int Bmat = (g == 0) ? 1 : 2;            /* g0: K_rb; g1,g2: K_gb */
    const int la   = lane & 31;
    const int kb16 = (lane >> 5) << 4;            /* 0 or 16 bytes */
    const int arow = i2 * 64 + la;
    const int brow = j2 * 64 + la;

    f32x16 acc[4];
#pragma unroll
    for (int i = 0; i < 4; ++i)
#pragma unroll
        for (int r = 0; r < 16; ++r) acc[i][r] = 0.0f;

    const int n0 = chunk * kchunk;

    f32x2 Ra, Ga, Ba, Rb, Gb, Bb;                 /* load ping-pong */
    f32x2 dd, rw2;                                /* current scalars */

    auto issue_ld = [&](int reg, f32x2& R, f32x2& G, f32x2& B) {
        const int n = n0 + reg * 32 + 2 * i16;
        R = *reinterpret_cast<const f32x2*>(Rp + n);
        G = *reinterpret_cast<const f32x2*>(Gp + n);
        B = *reinterpret_cast<const f32x2*>(Bp + n);
    };

    auto scalars = [&](f32x2 R, f32x2 G, f32x2 B) {
        const float C = 34.65735902799726547086f;   /* 50 * ln2 */
        float r0 = fminf(fmaxf(R.x, 0.0f), 1.0f);
        float r1 = fminf(fmaxf(R.y, 0.0f), 1.0f);
        float g0 = fminf(fmaxf(G.x, 0.0f), 1.0f);
        float g1 = fminf(fmaxf(G.y, 0.0f), 1.0f);
        float b0 = fminf(fmaxf(B.x, 0.0f), 1.0f);
        float b1 = fminf(fmaxf(B.y, 0.0f), 1.0f);
        /* mat0: rg, mat1: rb, mat2: gb -> pick inputs, 4 logs not 6 */
        const float x0a = (mat == 2) ? g0 : r0;
        const float x1a = (mat == 2) ? g1 : r1;
        const float y0a = (mat == 0) ? g0 : b0;
        const float y1a = (mat == 0) ? g1 : b1;
        dd.x = (__builtin_amdgcn_logf(x0a + EPSF)
              - __builtin_amdgcn_logf(y0a + EPSF)) * C;
        dd.y = (__builtin_amdgcn_logf(x1a + EPSF)
              - __builtin_amdgcn_logf(y1a + EPSF)) * C;
        const float s0 = __builtin_fmaf(r0, r0,
                          __builtin_fmaf(g0, g0,
                           __builtin_fmaf(b0, b0, EPSF)));
        const float s1 = __builtin_fmaf(r1, r1,
                          __builtin_fmaf(g1, g1,
                           __builtin_fmaf(b1, b1, EPSF)));
        rw2.x = __builtin_amdgcn_sqrtf(__builtin_amdgcn_sqrtf(s0));
        rw2.y = __builtin_amdgcn_sqrtf(__builtin_amdgcn_sqrtf(s1));
    };

    auto gen = [&](char* bp) {
        float m = MU0;
#pragma unroll
        for (int s = 0; s < 8; ++s) {              /* rows rbase + 16*s */
            const float ex = dd.x - m, ey = dd.y - m;
            const float tx = __builtin_fmaf(ex, ex, 1.0f);
            const float ty = __builtin_fmaf(ey, ey, 1.0f);
            const float vx = __builtin_amdgcn_rcpf(tx) * rw2.x;
            const float vy = __builtin_amdgcn_rcpf(ty) * rw2.y;
            *reinterpret_cast<unsigned*>(bp + s * 16 * ROWB) = pk2(vx, vy);
            m += MUSTEP;
        }
    };

    auto do_mfma = [&](const char* mp) {
        const char* Ab = mp + Amat * MATB;
        const char* Bb = mp + Bmat * MATB;
#pragma unroll
        for (int kb = 0; kb < 2; ++kb) {
            const int koff = kb * 32 + kb16;
            half8 a0 = *reinterpret_cast<const half8*>(Ab + arow * ROWB + koff);
            half8 a1 = *reinterpret_cast<const half8*>(Ab + (arow + 32) * ROWB + koff);
            half8 b0 = *reinterpret_cast<const half8*>(Bb + brow * ROWB + koff);
            half8 b1 = *reinterpret_cast<const half8*>(Bb + (brow + 32) * ROWB + koff);
            __builtin_amdgcn_s_setprio(1);
            acc[0] = __builtin_amdgcn_mfma_f32_32x32x16_f16(a0, b0, acc[0], 0, 0, 0);
            acc[1] = __builtin_amdgcn_mfma_f32_32x32x16_f16(a0, b1, acc[1], 0, 0, 0);
            acc[2] = __builtin_amdgcn_mfma_f32_32x32x16_f16(a1, b0, acc[2], 0, 0, 0);
            acc[3] = __builtin_amdgcn_mfma_f32_32x32x16_f16(a1, b1, acc[3], 0, 0, 0);
            __builtin_amdgcn_s_setprio(0);
        }
    };

    /* prologue: gen region 0 into buf0 */
    issue_ld(0, Ra, Ga, Ba);
    scalars(Ra, Ga, Ba);
    gen(genp0);
    issue_ld(1, Rb, Gb, Bb);
    __syncthreads();

    for (int rg = 0; rg < nreg; rg += 2) {
        /* body A: MFMA reg rg (buf0) || gen reg rg+1 -> buf1 */
        scalars(Rb, Gb, Bb);
        issue_ld(min(rg + 2, nreg - 1), Ra, Ga, Ba);
        gen(genp1);
        do_mfma(smat);
        __syncthreads();
        /* body B: MFMA reg rg+1 (buf1) || gen reg rg+2 -> buf0 */
        scalars(Ra, Ga, Ba);
        issue_ld(min(rg + 3, nreg - 1), Rb, Gb, Bb);
        if (rg + 2 < nreg) gen(genp0);
        do_mfma(smat + BUFB);
        __syncthreads();
    }

    /* ---- epilogue A: pack f16 pairs, coalesced u32 stores.
     * word = ((wave*4 + idx)*8 + rh)*64 + lane -- consistent bijection;
     * g-major 8192-word ranges match reduce_loss (wave = g*4 + tile).
     * norms+Hellinger are permutation-invariant (validated round 8). */
    unsigned* pb0 = parts + (size_t)blockIdx.x * PPW;
    float blksum = 0.0f;
#pragma unroll
    for (int idx = 0; idx < 4; ++idx) {
        unsigned* wp = pb0 + (size_t)((wave * 4 + idx) * 8) * 64 + lane;
#pragma unroll
        for (int rh = 0; rh < 8; ++rh) {
            wp[rh * 64] = pk2(acc[idx][2 * rh], acc[idx][2 * rh + 1]);
            blksum += acc[idx][2 * rh] + acc[idx][2 * rh + 1];
        }
    }

    /* ---- epilogue B: block contribution to norms[ib] ---- */
    for (int o = 32; o > 0; o >>= 1) blksum += __shfl_down(blksum, o, 64);
    if (lane == 0) wsum[wave] = blksum;
    __syncthreads();
    if (t == 0) {
        float s = 0.0f;
#pragma unroll
        for (int w = 0; w < 12; ++w) s += wsum[w];
        atomicAdd(&norms[ib], s);
    }
}

/* ------- kernel 2: fused parts-reduce + Hellinger + loss -------------- */
__global__ __launch_bounds__(256) void reduce_loss(
    const unsigned* __restrict__ parts, const float* __restrict__ norms,
    float* __restrict__ acc, int nchunk)
{
    const int i      = blockIdx.x * 256 + threadIdx.x;  /* < 98304 */
    const int comb12 = i >> 13;                         /* block-uniform */
    const int rest   = i & 8191;
    const int b      = comb12 / 3;
    const int g      = comb12 % 3;
    const unsigned* pp = parts + (size_t)(b * nchunk) * PPW + g * 8192 + rest;
    const unsigned* pt = parts + (size_t)((4 + b) * nchunk) * PPW + g * 8192 + rest;

    float hp0 = 0.0f, hp1 = 0.0f, ht0 = 0.0f, ht1 = 0.0f;
    int k = 0;
    for (; k + 8 <= nchunk; k += 8) {
#pragma unroll
        for (int j = 0; j < 8; ++j) {
            union { unsigned u; fp16x2 h; } a, c;
            a.u = pp[(size_t)(k + j) * PPW];
            c.u = pt[(size_t)(k + j) * PPW];
            hp0 += (float)a.h.x;  hp1 += (float)a.h.y;
            ht0 += (float)c.h.x;  ht1 += (float)c.h.y;
        }
    }
    for (; k < nchunk; ++k) {
        union { unsigned u; fp16x2 h; } a, c;
        a.u = pp[(size_t)k * PPW];
        c.u = pt[(size_t)k * PPW];
        hp0 += (float)a.h.x;  hp1 += (float)a.h.y;
        ht0 += (float)c.h.x;  ht1 += (float)c.h.y;
    }

    const float rp = __builtin_amdgcn_rcpf(norms[b] + EPSF);
    const float rt = __builtin_amdgcn_rcpf(norms[4 + b] + EPSF);
    const float d0 = __builtin_amdgcn_sqrtf(ht0 * rt)
                   - __builtin_amdgcn_sqrtf(hp0 * rp);
    const float d1 = __builtin_amdgcn_sqrtf(ht1 * rt)
                   - __builtin_amdgcn_sqrtf(hp1 * rp);
    float s = __builtin_fmaf(d0, d0, d1 * d1);
    for (int o = 32; o > 0; o >>= 1) s += __shfl_down(s, o, 64);
    __shared__ float wsum[4];
    if ((threadIdx.x & 63) == 0) wsum[threadIdx.x >> 6] = s;
    __syncthreads();
    if (threadIdx.x == 0) atomicAdd(acc, wsum[0] + wsum[1] + wsum[2] + wsum[3]);
}

/* ---------------- kernel 3: final scalar ------------------------------ */
__global__ void final_k(const float* __restrict__ acc, float* __restrict__ out)
{
    out[0] = __builtin_amdgcn_sqrtf(acc[0]) * 0.70710678118654752440f * 0.25f;
}

extern "C" void kernel_launch(void* const* d_in, const int* in_sizes, int n_in,
                              void* d_out, int out_size, void* d_ws, size_t ws_size,
                              hipStream_t stream)
{
    const float* pred = (const float*)d_in[0];
    const float* tgt  = (const float*)d_in[1];
    float* ws  = (float*)d_ws;
    float* out = (float*)d_out;

    float*    norms = ws;             /* 8 floats                          */
    float*    acc   = ws + 8;         /* 1 float                           */
    unsigned* parts = (unsigned*)(ws + 16);     /* 8*nchunk*PPW u32        */

    int nchunk = NCHUNK;              /* 32 -> 256 blocks, ~25 MB parts */
    while (nchunk > 1) {
        const size_t need = (16 + (size_t)8 * nchunk * PPW) * sizeof(float);
        if (need <= ws_size) break;
        nchunk >>= 1;
    }

    (void)hipMemsetAsync(ws, 0, 9 * sizeof(float), stream);  /* norms+acc */

    hist_mfma<<<8 * nchunk, 768, 0, stream>>>(pred, tgt, parts, norms, nchunk);
    reduce_loss<<<12 * 8192 / 256, 256, 0, stream>>>(parts, norms, acc, nchunk);
    final_k<<<1, 1, 0, stream>>>(acc, out);
}